// Round 17
// baseline (53.062 us; speedup 1.0000x reference)
//
#include <hip/hip_runtime.h>
#include <math.h>

#define CAP 64        // fixed edge slots per node; cnt>CAP takes the (never-hit) fallback
#define CSTRIDE 16    // one counter per 64B L2 line

#define LOG2E    1.44269504088896341f
#define LOG2E_3  0.48089834696298780f   // log2(e)/3

__device__ __forceinline__ float celu3(float x) {
    // celu(x,3) = max(x,0) + 3*(2^(min(x,0)*log2e/3) - 1); exp2f is native v_exp_f32
    return fmaxf(x, 0.0f) + 3.0f * (exp2f(fminf(x, 0.0f) * LOG2E_3) - 1.0f);
}

// DPP-based reductions: pure VALU, no LDS pipe on the chain.
template <int CTRL>
__device__ __forceinline__ float dpp_add(float v) {
    int o = __builtin_amdgcn_update_dpp(0, __float_as_int(v), CTRL, 0xf, 0xf, true);
    return v + __int_as_float(o);
}
__device__ __forceinline__ float red16(float v) {
    v = dpp_add<0xB1>(v);    // quad_perm xor1
    v = dpp_add<0x4E>(v);    // quad_perm xor2
    v = dpp_add<0x124>(v);   // row_ror:4
    v = dpp_add<0x128>(v);   // row_ror:8
    return v;
}
__device__ __forceinline__ float wave_sum64(float v) {
    v = red16(v);
    v += __shfl_xor(v, 16, 64);
    v += __shfl_xor(v, 32, 64);
    return v;
}

// ---- K1: zero padded counts + a1 (one launch) ------------------------------

__global__ __launch_bounds__(256) void init_kernel(
    int* __restrict__ counts, int N,
    const float* __restrict__ feat, const float* __restrict__ w1,
    float* __restrict__ a1)
{
    int nz = N * CSTRIDE;
    int nblk_zero = (nz + 255) / 256;
    if ((int)blockIdx.x < nblk_zero) {
        int i = blockIdx.x * 256 + threadIdx.x;
        if (i < nz) counts[i] = 0;
        return;
    }
    int n = (blockIdx.x - nblk_zero) * 4 + (threadIdx.x >> 6);
    int lane = threadIdx.x & 63;
    if (n >= N) return;
    float f = feat[(long)n * 64 + lane];
    float s[4];
#pragma unroll
    for (int h = 0; h < 4; ++h) s[h] = wave_sum64(f * w1[h * 64 + lane]);
    if (lane < 4) a1[n * 4 + lane] = celu3(s[lane]);
}

// ---- K2: hist + direct slot scatter (padded counters) ----------------------

__global__ __launch_bounds__(256) void hist_kernel(
    const int* __restrict__ seg, int* __restrict__ counts,
    int* __restrict__ elist, int E)
{
    int i = blockIdx.x * 256 + threadIdx.x;
    int stride = gridDim.x * 256;
    for (; i < E; i += stride) {
        int s = seg[i];
        int r = atomicAdd(&counts[s * CSTRIDE], 1);
        if (r < CAP) elist[s * CAP + r] = i;
    }
}

// ---- K3: fused dots + fixed-shift softmax + aggregate ----------------------
// ONE WAVE PER BLOCK, one node per block. lane = (g = row-group, q = dim-quad).
// SOFTWARE-PIPELINED: chunk c+1's shfl+load issue before chunk c's compute,
// hiding the bpermute+L3 latency chain under compute. meta read exactly once.

__global__ __launch_bounds__(64) void fused_kernel(
    const float* __restrict__ meta, const float* __restrict__ w2,
    const float* __restrict__ a1, const int* __restrict__ counts,
    const int* __restrict__ elist, const int* __restrict__ seg,
    float* __restrict__ out, int N, int E)
{
    int lane = threadIdx.x;
    int n = blockIdx.x;
    if (n >= N) return;

    int cnt = counts[n * CSTRIDE];
    int g = lane >> 4;       // row-group (gather) / head (store)
    int q = lane & 15;       // dim-quad
    long ob = (long)n * 256 + g * 64 + q * 4;

    if (cnt == 0) {
        float4 z = {0.f, 0.f, 0.f, 0.f};
        *(float4*)(out + ob) = z;
        return;
    }

    float4 a1v = *(const float4*)(a1 + (long)n * 4);

    if (cnt <= CAP) {
        // per-lane w2 slice: head h, dims 4q..4q+3
        float4 w2q0 = *(const float4*)(w2 + 0 * 64 + q * 4);
        float4 w2q1 = *(const float4*)(w2 + 1 * 64 + q * 4);
        float4 w2q2 = *(const float4*)(w2 + 2 * 64 + q * 4);
        float4 w2q3 = *(const float4*)(w2 + 3 * 64 + q * 4);

        int eid_l = (lane < cnt) ? elist[n * CAP + lane] : 0;
        const float* meta_q = meta + q * 4;    // per-lane base, hoisted

        float sp0 = 0.f, sp1 = 0.f, sp2 = 0.f, sp3 = 0.f;
        float4 acc0 = {0,0,0,0}, acc1 = {0,0,0,0}, acc2 = {0,0,0,0}, acc3 = {0,0,0,0};

        int nch = (cnt + 3) >> 2;

        // prologue: chunk 0's eid + load in flight
        int eid = __shfl(eid_l, g);            // j = g for c=0 (g<4<=cnt? g may exceed cnt-1: clamp)
        // clamp for cnt<4: row j>=cnt contributes p=0, load from slot 0 is safe
        if (g >= cnt) eid = __shfl(eid_l, 0);
        float4 v = *(const float4*)(meta_q + (long)eid * 64);

#pragma unroll 4
        for (int c = 0; c < nch; ++c) {
            // ---- prefetch chunk c+1 (clamped; last iter loads a dup, harmless)
            int jn = (c + 1) * 4 + g;
            int jc = (jn < cnt) ? jn : 0;
            int eidn = __shfl(eid_l, jc);
            float4 vn = *(const float4*)(meta_q + (long)eidn * 64);

            // ---- compute chunk c from v
            bool vr = (c * 4 + g) < cnt;
            float4 ef;
            ef.x = celu3(v.x); ef.y = celu3(v.y); ef.z = celu3(v.z); ef.w = celu3(v.w);

            float d0 = ef.x * w2q0.x + ef.y * w2q0.y + ef.z * w2q0.z + ef.w * w2q0.w;
            float d1 = ef.x * w2q1.x + ef.y * w2q1.y + ef.z * w2q1.z + ef.w * w2q1.w;
            float d2 = ef.x * w2q2.x + ef.y * w2q2.y + ef.z * w2q2.z + ef.w * w2q2.w;
            float d3 = ef.x * w2q3.x + ef.y * w2q3.y + ef.z * w2q3.z + ef.w * w2q3.w;
            d0 = red16(d0); d1 = red16(d1); d2 = red16(d2); d3 = red16(d3);

            float A0 = vr ? celu3(a1v.x + d0) : -INFINITY;
            float A1 = vr ? celu3(a1v.y + d1) : -INFINITY;
            float A2 = vr ? celu3(a1v.z + d2) : -INFINITY;
            float A3 = vr ? celu3(a1v.w + d3) : -INFINITY;

            // fixed-shift softmax numerator (0 for invalid rows); native exp2
            float p0 = exp2f(fminf(A0, 80.f) * LOG2E);
            float p1 = exp2f(fminf(A1, 80.f) * LOG2E);
            float p2 = exp2f(fminf(A2, 80.f) * LOG2E);
            float p3 = exp2f(fminf(A3, 80.f) * LOG2E);

            sp0 += p0; sp1 += p1; sp2 += p2; sp3 += p3;

            acc0.x = fmaf(p0, ef.x, acc0.x); acc0.y = fmaf(p0, ef.y, acc0.y);
            acc0.z = fmaf(p0, ef.z, acc0.z); acc0.w = fmaf(p0, ef.w, acc0.w);
            acc1.x = fmaf(p1, ef.x, acc1.x); acc1.y = fmaf(p1, ef.y, acc1.y);
            acc1.z = fmaf(p1, ef.z, acc1.z); acc1.w = fmaf(p1, ef.w, acc1.w);
            acc2.x = fmaf(p2, ef.x, acc2.x); acc2.y = fmaf(p2, ef.y, acc2.y);
            acc2.z = fmaf(p2, ef.z, acc2.z); acc2.w = fmaf(p2, ef.w, acc2.w);
            acc3.x = fmaf(p3, ef.x, acc3.x); acc3.y = fmaf(p3, ef.y, acc3.y);
            acc3.z = fmaf(p3, ef.z, acc3.z); acc3.w = fmaf(p3, ef.w, acc3.w);

            v = vn;
        }

        // reduce partials across row-groups (xor 16, 32)
        sp0 += __shfl_xor(sp0, 16); sp0 += __shfl_xor(sp0, 32);
        sp1 += __shfl_xor(sp1, 16); sp1 += __shfl_xor(sp1, 32);
        sp2 += __shfl_xor(sp2, 16); sp2 += __shfl_xor(sp2, 32);
        sp3 += __shfl_xor(sp3, 16); sp3 += __shfl_xor(sp3, 32);

        acc0.x += __shfl_xor(acc0.x, 16); acc0.x += __shfl_xor(acc0.x, 32);
        acc0.y += __shfl_xor(acc0.y, 16); acc0.y += __shfl_xor(acc0.y, 32);
        acc0.z += __shfl_xor(acc0.z, 16); acc0.z += __shfl_xor(acc0.z, 32);
        acc0.w += __shfl_xor(acc0.w, 16); acc0.w += __shfl_xor(acc0.w, 32);
        acc1.x += __shfl_xor(acc1.x, 16); acc1.x += __shfl_xor(acc1.x, 32);
        acc1.y += __shfl_xor(acc1.y, 16); acc1.y += __shfl_xor(acc1.y, 32);
        acc1.z += __shfl_xor(acc1.z, 16); acc1.z += __shfl_xor(acc1.z, 32);
        acc1.w += __shfl_xor(acc1.w, 16); acc1.w += __shfl_xor(acc1.w, 32);
        acc2.x += __shfl_xor(acc2.x, 16); acc2.x += __shfl_xor(acc2.x, 32);
        acc2.y += __shfl_xor(acc2.y, 16); acc2.y += __shfl_xor(acc2.y, 32);
        acc2.z += __shfl_xor(acc2.z, 16); acc2.z += __shfl_xor(acc2.z, 32);
        acc2.w += __shfl_xor(acc2.w, 16); acc2.w += __shfl_xor(acc2.w, 32);
        acc3.x += __shfl_xor(acc3.x, 16); acc3.x += __shfl_xor(acc3.x, 32);
        acc3.y += __shfl_xor(acc3.y, 16); acc3.y += __shfl_xor(acc3.y, 32);
        acc3.z += __shfl_xor(acc3.z, 16); acc3.z += __shfl_xor(acc3.z, 32);
        acc3.w += __shfl_xor(acc3.w, 16); acc3.w += __shfl_xor(acc3.w, 32);

        float rs0 = 1.f / sp0, rs1 = 1.f / sp1, rs2 = 1.f / sp2, rs3 = 1.f / sp3;

        float4 av = (g == 0) ? acc0 : (g == 1) ? acc1 : (g == 2) ? acc2 : acc3;
        float rg = (g == 0) ? rs0 : (g == 1) ? rs1 : (g == 2) ? rs2 : rs3;
        float4 o;
        o.x = celu3(av.x * rg); o.y = celu3(av.y * rg);
        o.z = celu3(av.z * rg); o.w = celu3(av.w * rg);
        *(float4*)(out + ob) = o;
        return;
    }

    // ---- fallback (cnt > CAP): brute-force seg scan, lane = dim. correct, never hot
    {
        float a10 = a1v.x, a11 = a1v.y, a12 = a1v.z, a13 = a1v.w;
        float w2v0 = w2[0 * 64 + lane], w2v1 = w2[1 * 64 + lane];
        float w2v2 = w2[2 * 64 + lane], w2v3 = w2[3 * 64 + lane];
        float m0 = -INFINITY, m1 = -INFINITY, m2 = -INFINITY, m3 = -INFINITY;
        float s0 = 0.f, s1 = 0.f, s2 = 0.f, s3 = 0.f;
        float ac0 = 0.f, ac1 = 0.f, ac2 = 0.f, ac3 = 0.f;
        for (int base = 0; base < E; base += 64) {
            int e = base + lane;
            bool hit = (e < E) && (seg[e] == n);
            unsigned long long ball = __ballot(hit);
            while (ball) {
                int b = __ffsll((long long)ball) - 1;
                ball &= ball - 1;
                int eid = base + b;
                float eft = celu3(meta[(long)eid * 64 + lane]);
                float d0 = wave_sum64(eft * w2v0);
                float d1 = wave_sum64(eft * w2v1);
                float d2 = wave_sum64(eft * w2v2);
                float d3 = wave_sum64(eft * w2v3);
                float A0 = celu3(a10 + d0), A1 = celu3(a11 + d1);
                float A2 = celu3(a12 + d2), A3 = celu3(a13 + d3);
                float nm0 = fmaxf(m0, A0), nm1 = fmaxf(m1, A1);
                float nm2 = fmaxf(m2, A2), nm3 = fmaxf(m3, A3);
                float al0 = __expf(m0 - nm0), al1 = __expf(m1 - nm1);
                float al2 = __expf(m2 - nm2), al3 = __expf(m3 - nm3);
                float p0 = __expf(A0 - nm0), p1 = __expf(A1 - nm1);
                float p2 = __expf(A2 - nm2), p3 = __expf(A3 - nm3);
                s0 = fmaf(al0, s0, p0); s1 = fmaf(al1, s1, p1);
                s2 = fmaf(al2, s2, p2); s3 = fmaf(al3, s3, p3);
                ac0 = fmaf(p0, eft, al0 * ac0); ac1 = fmaf(p1, eft, al1 * ac1);
                ac2 = fmaf(p2, eft, al2 * ac2); ac3 = fmaf(p3, eft, al3 * ac3);
                m0 = nm0; m1 = nm1; m2 = nm2; m3 = nm3;
            }
        }
        long ob2 = (long)n * 256 + lane;
        out[ob2]       = celu3(ac0 / s0);
        out[ob2 + 64]  = celu3(ac1 / s1);
        out[ob2 + 128] = celu3(ac2 / s2);
        out[ob2 + 192] = celu3(ac3 / s3);
    }
}

// ---- launch ----------------------------------------------------------------

extern "C" void kernel_launch(void* const* d_in, const int* in_sizes, int n_in,
                              void* d_out, int out_size, void* d_ws, size_t ws_size,
                              hipStream_t stream)
{
    const float* feat = (const float*)d_in[0];
    const float* meta = (const float*)d_in[1];
    const float* w1   = (const float*)d_in[2];
    const float* w2   = (const float*)d_in[3];
    const int*   seg  = (const int*)d_in[4];
    float* out = (float*)d_out;

    int N = in_sizes[0] / 64;
    int E = in_sizes[4];

    float* a1   = (float*)d_ws;                    // N*4 floats
    int* counts = (int*)(a1 + (size_t)N * 4);      // N*CSTRIDE ints (padded)
    int* elist  = counts + (size_t)N * CSTRIDE;    // N*CAP ints

    int nblk_zero = (N * CSTRIDE + 255) / 256;
    int nblk_a1   = (N + 3) / 4;

    init_kernel<<<nblk_zero + nblk_a1, 256, 0, stream>>>(counts, N, feat, w1, a1);
    hist_kernel<<<512, 256, 0, stream>>>(seg, counts, elist, E);
    fused_kernel<<<N, 64, 0, stream>>>(meta, w2, a1, counts, elist, seg, out, N, E);
}

// Round 18
// 45.131 us; speedup vs baseline: 1.1758x; 1.1758x over previous
//
#include <hip/hip_runtime.h>
#include <math.h>

#define CAP 64        // fixed edge slots per node; cnt>CAP takes the (never-hit) fallback
#define CSTRIDE 16    // one counter per 64B L2 line

#define LOG2E    1.44269504088896341f
#define LOG2E_3  0.48089834696298780f   // log2(e)/3

__device__ __forceinline__ float celu3(float x) {
    // celu(x,3) = max(x,0) + 3*(2^(min(x,0)*log2e/3) - 1); exp2f = native v_exp_f32
    return fmaxf(x, 0.0f) + 3.0f * (exp2f(fminf(x, 0.0f) * LOG2E_3) - 1.0f);
}

// DPP helpers: pure VALU, no LDS pipe on the chain. ctrl must be immediate.
template <int CTRL>
__device__ __forceinline__ float dpp_add(float v) {
    int o = __builtin_amdgcn_update_dpp(0, __float_as_int(v), CTRL, 0xf, 0xf, true);
    return v + __int_as_float(o);
}
template <int CTRL>
__device__ __forceinline__ float dpp_mov(float v) {
    int o = __builtin_amdgcn_update_dpp(0, __float_as_int(v), CTRL, 0xf, 0xf, true);
    return __int_as_float(o);
}
__device__ __forceinline__ float red16(float v) {
    v = dpp_add<0xB1>(v);    // quad_perm xor1
    v = dpp_add<0x4E>(v);    // quad_perm xor2
    v = dpp_add<0x124>(v);   // row_ror:4
    v = dpp_add<0x128>(v);   // row_ror:8
    return v;
}
__device__ __forceinline__ float wave_sum64(float v) {
    v = red16(v);
    v += __shfl_xor(v, 16, 64);
    v += __shfl_xor(v, 32, 64);
    return v;
}

// ---- K1: zero padded counts + a1 (one launch) ------------------------------

__global__ __launch_bounds__(256) void init_kernel(
    int* __restrict__ counts, int N,
    const float* __restrict__ feat, const float* __restrict__ w1,
    float* __restrict__ a1)
{
    int nz = N * CSTRIDE;
    int nblk_zero = (nz + 255) / 256;
    if ((int)blockIdx.x < nblk_zero) {
        int i = blockIdx.x * 256 + threadIdx.x;
        if (i < nz) counts[i] = 0;
        return;
    }
    int n = (blockIdx.x - nblk_zero) * 4 + (threadIdx.x >> 6);
    int lane = threadIdx.x & 63;
    if (n >= N) return;
    float f = feat[(long)n * 64 + lane];
    float s[4];
#pragma unroll
    for (int h = 0; h < 4; ++h) s[h] = wave_sum64(f * w1[h * 64 + lane]);
    if (lane < 4) a1[n * 4 + lane] = celu3(s[lane]);
}

// ---- K2: hist + direct slot scatter (padded counters) ----------------------

__global__ __launch_bounds__(256) void hist_kernel(
    const int* __restrict__ seg, int* __restrict__ counts,
    int* __restrict__ elist, int E)
{
    int i = blockIdx.x * 256 + threadIdx.x;
    int stride = gridDim.x * 256;
    for (; i < E; i += stride) {
        int s = seg[i];
        int r = atomicAdd(&counts[s * CSTRIDE], 1);
        if (r < CAP) elist[s * CAP + r] = i;
    }
}

// ---- K3: fused dots + fixed-shift softmax + aggregate ----------------------
// ONE WAVE PER BLOCK, one node per block. lane = (g = row-group, q = dim-quad,
// t = quad position = head for the transposed A/p compute).
// TRANSPOSED A/p: after quad-level reduce each lane finishes only its head t's
// dot (ror4+ror8 on one value), computes A/p once (2 transcendentals vs 8),
// then quad_perm-broadcasts p back. meta read exactly once.

__global__ __launch_bounds__(64) void fused_kernel(
    const float* __restrict__ meta, const float* __restrict__ w2,
    const float* __restrict__ a1, const int* __restrict__ counts,
    const int* __restrict__ elist, const int* __restrict__ seg,
    float* __restrict__ out, int N, int E)
{
    int lane = threadIdx.x;
    int n = blockIdx.x;
    if (n >= N) return;

    int cnt = counts[n * CSTRIDE];
    int g = lane >> 4;       // row-group (gather) / head (store)
    int q = lane & 15;       // dim-quad
    int t = lane & 3;        // quad position = my head in the transposed compute
    long ob = (long)n * 256 + g * 64 + q * 4;

    if (cnt == 0) {
        float4 z = {0.f, 0.f, 0.f, 0.f};
        *(float4*)(out + ob) = z;
        return;
    }

    float4 a1v = *(const float4*)(a1 + (long)n * 4);

    if (cnt <= CAP) {
        // per-lane w2 slice: head h, dims 4q..4q+3
        float4 w2q0 = *(const float4*)(w2 + 0 * 64 + q * 4);
        float4 w2q1 = *(const float4*)(w2 + 1 * 64 + q * 4);
        float4 w2q2 = *(const float4*)(w2 + 2 * 64 + q * 4);
        float4 w2q3 = *(const float4*)(w2 + 3 * 64 + q * 4);

        // hoisted: my head's a1
        float a1sel = (t == 0) ? a1v.x : (t == 1) ? a1v.y : (t == 2) ? a1v.z : a1v.w;

        int eid_l = (lane < cnt) ? elist[n * CAP + lane] : 0;
        const float* meta_q = meta + q * 4;

        float sp = 0.f;   // head-t partial denominator (per group)
        float4 acc0 = {0,0,0,0}, acc1 = {0,0,0,0}, acc2 = {0,0,0,0}, acc3 = {0,0,0,0};

        int nch = (cnt + 3) >> 2;
#pragma unroll 8
        for (int c = 0; c < nch; ++c) {
            int j = c * 4 + g;                 // my row this chunk (<=63)
            bool vr = j < cnt;
            int eid = __shfl(eid_l, j);
            float4 v = *(const float4*)(meta_q + (long)eid * 64);
            float4 ef;
            ef.x = celu3(v.x); ef.y = celu3(v.y); ef.z = celu3(v.z); ef.w = celu3(v.w);

            // partial dots for all 4 heads over my 4 dims
            float d0 = ef.x * w2q0.x + ef.y * w2q0.y + ef.z * w2q0.z + ef.w * w2q0.w;
            float d1 = ef.x * w2q1.x + ef.y * w2q1.y + ef.z * w2q1.z + ef.w * w2q1.w;
            float d2 = ef.x * w2q2.x + ef.y * w2q2.y + ef.z * w2q2.z + ef.w * w2q2.w;
            float d3 = ef.x * w2q3.x + ef.y * w2q3.y + ef.z * w2q3.z + ef.w * w2q3.w;

            // quad-level sums for all heads, then finish ONLY my head t
            d0 = dpp_add<0xB1>(d0); d1 = dpp_add<0xB1>(d1);
            d2 = dpp_add<0xB1>(d2); d3 = dpp_add<0xB1>(d3);
            d0 = dpp_add<0x4E>(d0); d1 = dpp_add<0x4E>(d1);
            d2 = dpp_add<0x4E>(d2); d3 = dpp_add<0x4E>(d3);
            float dsel = (t == 0) ? d0 : (t == 1) ? d1 : (t == 2) ? d2 : d3;
            dsel = dpp_add<0x124>(dsel);       // row_ror:4
            dsel = dpp_add<0x128>(dsel);       // row_ror:8 -> full 64-dim dot, head t

            // A/p once per lane (head t); p = 0 for invalid rows (exp2(-inf)=0)
            float A = vr ? celu3(a1sel + dsel) : -INFINITY;
            float p = exp2f(fminf(A, 80.f) * LOG2E);
            sp += p;

            // broadcast quad's 4 head-p values to all quad lanes
            float b0 = dpp_mov<0x00>(p);       // quad_perm [0,0,0,0]
            float b1 = dpp_mov<0x55>(p);       // quad_perm [1,1,1,1]
            float b2 = dpp_mov<0xAA>(p);       // quad_perm [2,2,2,2]
            float b3 = dpp_mov<0xFF>(p);       // quad_perm [3,3,3,3]

            acc0.x = fmaf(b0, ef.x, acc0.x); acc0.y = fmaf(b0, ef.y, acc0.y);
            acc0.z = fmaf(b0, ef.z, acc0.z); acc0.w = fmaf(b0, ef.w, acc0.w);
            acc1.x = fmaf(b1, ef.x, acc1.x); acc1.y = fmaf(b1, ef.y, acc1.y);
            acc1.z = fmaf(b1, ef.z, acc1.z); acc1.w = fmaf(b1, ef.w, acc1.w);
            acc2.x = fmaf(b2, ef.x, acc2.x); acc2.y = fmaf(b2, ef.y, acc2.y);
            acc2.z = fmaf(b2, ef.z, acc2.z); acc2.w = fmaf(b2, ef.w, acc2.w);
            acc3.x = fmaf(b3, ef.x, acc3.x); acc3.y = fmaf(b3, ef.y, acc3.y);
            acc3.z = fmaf(b3, ef.z, acc3.z); acc3.w = fmaf(b3, ef.w, acc3.w);
        }

        // sp: within a group, same-t lanes hold identical values; sum across groups
        sp += __shfl_xor(sp, 16); sp += __shfl_xor(sp, 32);
        // every lane now holds head-(lane&3) total; lane g (g<4) holds head g

        // acc reduce across row-groups (xor 16, 32)
        acc0.x += __shfl_xor(acc0.x, 16); acc0.x += __shfl_xor(acc0.x, 32);
        acc0.y += __shfl_xor(acc0.y, 16); acc0.y += __shfl_xor(acc0.y, 32);
        acc0.z += __shfl_xor(acc0.z, 16); acc0.z += __shfl_xor(acc0.z, 32);
        acc0.w += __shfl_xor(acc0.w, 16); acc0.w += __shfl_xor(acc0.w, 32);
        acc1.x += __shfl_xor(acc1.x, 16); acc1.x += __shfl_xor(acc1.x, 32);
        acc1.y += __shfl_xor(acc1.y, 16); acc1.y += __shfl_xor(acc1.y, 32);
        acc1.z += __shfl_xor(acc1.z, 16); acc1.z += __shfl_xor(acc1.z, 32);
        acc1.w += __shfl_xor(acc1.w, 16); acc1.w += __shfl_xor(acc1.w, 32);
        acc2.x += __shfl_xor(acc2.x, 16); acc2.x += __shfl_xor(acc2.x, 32);
        acc2.y += __shfl_xor(acc2.y, 16); acc2.y += __shfl_xor(acc2.y, 32);
        acc2.z += __shfl_xor(acc2.z, 16); acc2.z += __shfl_xor(acc2.z, 32);
        acc2.w += __shfl_xor(acc2.w, 16); acc2.w += __shfl_xor(acc2.w, 32);
        acc3.x += __shfl_xor(acc3.x, 16); acc3.x += __shfl_xor(acc3.x, 32);
        acc3.y += __shfl_xor(acc3.y, 16); acc3.y += __shfl_xor(acc3.y, 32);
        acc3.z += __shfl_xor(acc3.z, 16); acc3.z += __shfl_xor(acc3.z, 32);
        acc3.w += __shfl_xor(acc3.w, 16); acc3.w += __shfl_xor(acc3.w, 32);

        float rg = 1.f / __int_as_float(__builtin_amdgcn_ds_bpermute(g << 2, __float_as_int(sp)));

        float4 av = (g == 0) ? acc0 : (g == 1) ? acc1 : (g == 2) ? acc2 : acc3;
        float4 o;
        o.x = celu3(av.x * rg); o.y = celu3(av.y * rg);
        o.z = celu3(av.z * rg); o.w = celu3(av.w * rg);
        *(float4*)(out + ob) = o;
        return;
    }

    // ---- fallback (cnt > CAP): brute-force seg scan, lane = dim. correct, never hot
    {
        float a10 = a1v.x, a11 = a1v.y, a12 = a1v.z, a13 = a1v.w;
        float w2v0 = w2[0 * 64 + lane], w2v1 = w2[1 * 64 + lane];
        float w2v2 = w2[2 * 64 + lane], w2v3 = w2[3 * 64 + lane];
        float m0 = -INFINITY, m1 = -INFINITY, m2 = -INFINITY, m3 = -INFINITY;
        float s0 = 0.f, s1 = 0.f, s2 = 0.f, s3 = 0.f;
        float ac0 = 0.f, ac1 = 0.f, ac2 = 0.f, ac3 = 0.f;
        for (int base = 0; base < E; base += 64) {
            int e = base + lane;
            bool hit = (e < E) && (seg[e] == n);
            unsigned long long ball = __ballot(hit);
            while (ball) {
                int b = __ffsll((long long)ball) - 1;
                ball &= ball - 1;
                int eid = base + b;
                float eft = celu3(meta[(long)eid * 64 + lane]);
                float d0 = wave_sum64(eft * w2v0);
                float d1 = wave_sum64(eft * w2v1);
                float d2 = wave_sum64(eft * w2v2);
                float d3 = wave_sum64(eft * w2v3);
                float A0 = celu3(a10 + d0), A1 = celu3(a11 + d1);
                float A2 = celu3(a12 + d2), A3 = celu3(a13 + d3);
                float nm0 = fmaxf(m0, A0), nm1 = fmaxf(m1, A1);
                float nm2 = fmaxf(m2, A2), nm3 = fmaxf(m3, A3);
                float al0 = __expf(m0 - nm0), al1 = __expf(m1 - nm1);
                float al2 = __expf(m2 - nm2), al3 = __expf(m3 - nm3);
                float p0 = __expf(A0 - nm0), p1 = __expf(A1 - nm1);
                float p2 = __expf(A2 - nm2), p3 = __expf(A3 - nm3);
                s0 = fmaf(al0, s0, p0); s1 = fmaf(al1, s1, p1);
                s2 = fmaf(al2, s2, p2); s3 = fmaf(al3, s3, p3);
                ac0 = fmaf(p0, eft, al0 * ac0); ac1 = fmaf(p1, eft, al1 * ac1);
                ac2 = fmaf(p2, eft, al2 * ac2); ac3 = fmaf(p3, eft, al3 * ac3);
                m0 = nm0; m1 = nm1; m2 = nm2; m3 = nm3;
            }
        }
        long ob2 = (long)n * 256 + lane;
        out[ob2]       = celu3(ac0 / s0);
        out[ob2 + 64]  = celu3(ac1 / s1);
        out[ob2 + 128] = celu3(ac2 / s2);
        out[ob2 + 192] = celu3(ac3 / s3);
    }
}

// ---- launch ----------------------------------------------------------------

extern "C" void kernel_launch(void* const* d_in, const int* in_sizes, int n_in,
                              void* d_out, int out_size, void* d_ws, size_t ws_size,
                              hipStream_t stream)
{
    const float* feat = (const float*)d_in[0];
    const float* meta = (const float*)d_in[1];
    const float* w1   = (const float*)d_in[2];
    const float* w2   = (const float*)d_in[3];
    const int*   seg  = (const int*)d_in[4];
    float* out = (float*)d_out;

    int N = in_sizes[0] / 64;
    int E = in_sizes[4];

    float* a1   = (float*)d_ws;                    // N*4 floats
    int* counts = (int*)(a1 + (size_t)N * 4);      // N*CSTRIDE ints (padded)
    int* elist  = counts + (size_t)N * CSTRIDE;    // N*CAP ints

    int nblk_zero = (N * CSTRIDE + 255) / 256;
    int nblk_a1   = (N + 3) / 4;

    init_kernel<<<nblk_zero + nblk_a1, 256, 0, stream>>>(counts, N, feat, w1, a1);
    hist_kernel<<<512, 256, 0, stream>>>(seg, counts, elist, E);
    fused_kernel<<<N, 64, 0, stream>>>(meta, w2, a1, counts, elist, seg, out, N, E);
}